// Round 14
// baseline (240.675 us; speedup 1.0000x reference)
//
#include <hip/hip_runtime.h>
#include <hip/hip_bf16.h>

#define N_NODES 50000
#define N_EDGES 800000
#define CAP 128   // fixed CSR bucket capacity per node (Binomial(800k,1/50k) max deg ~45)

typedef __attribute__((ext_vector_type(8))) short short8;
typedef __attribute__((ext_vector_type(4))) float floatx4;

__device__ __forceinline__ float b2f(unsigned short h) {
    union { unsigned int u; float f; } v; v.u = ((unsigned int)h) << 16; return v.f;
}
__device__ __forceinline__ unsigned short f2b(float f) {
    union { float f; unsigned int u; } v; v.f = f;
    unsigned int r = v.u + 0x7fffu + ((v.u >> 16) & 1u);
    return (unsigned short)(r >> 16);
}

// ---------------- fused: weight swizzle + x convert (float4) + edge rank&scatter (INTERLEAVED) ----------------
// b % 9 == 0 -> edge chunk b/9 (822 slots, 782 active chunks of 1024 edges):
//   each thread owns 4 edges (strided 256 for coalesced dst/src loads) ->
//   4 INDEPENDENT atomicAdd->store chains in flight per lane (r13 had 1 chain/lane
//   and was chain-latency bound at 51us despite 60% occupancy).
// else id = b - b/9 - 1: id < 320 -> weight swizzle; else x fp32->bf16 (float4/thread)
// Interleave keeps atomic-pipe and HBM-stream blocks co-resident (r9/r10 lesson).
__global__ void prep_conv_rs(const float* __restrict__ x, unsigned short* __restrict__ xb,
                             const float* __restrict__ Ws1, const float* __restrict__ Wn1,
                             const float* __restrict__ Ws2, const float* __restrict__ Wn2,
                             const float* __restrict__ Ws3, const float* __restrict__ Wn3,
                             unsigned short* __restrict__ wsw,
                             const int* __restrict__ src, const int* __restrict__ dst,
                             int* __restrict__ cnt, unsigned short* __restrict__ esrc16) {
    int b = blockIdx.x;
    int q9 = b / 9;
    if (b - q9 * 9 == 0) {
        int e0 = q9 * 1024 + threadIdx.x;
        if (e0 + 768 < N_EDGES) {            // full chunk: 4 unguarded independent chains
            int ea = e0, eb = e0 + 256, ec = e0 + 512, ed = e0 + 768;
            int da = dst[ea], db = dst[eb], dc = dst[ec], dd = dst[ed];
            int sa = src[ea], sb = src[eb], sc = src[ec], sd = src[ed];
            int ra = atomicAdd(&cnt[da], 1);
            int rb = atomicAdd(&cnt[db], 1);
            int rc = atomicAdd(&cnt[dc], 1);
            int rd = atomicAdd(&cnt[dd], 1);
            if (ra < CAP) esrc16[(size_t)da * CAP + ra] = (unsigned short)sa;
            if (rb < CAP) esrc16[(size_t)db * CAP + rb] = (unsigned short)sb;
            if (rc < CAP) esrc16[(size_t)dc * CAP + rc] = (unsigned short)sc;
            if (rd < CAP) esrc16[(size_t)dd * CAP + rd] = (unsigned short)sd;
        } else {                              // tail chunk: guarded
#pragma unroll
            for (int u = 0; u < 4; ++u) {
                int e = e0 + u * 256;
                if (e < N_EDGES) {
                    int d = dst[e];
                    int r = atomicAdd(&cnt[d], 1);
                    if (r < CAP) esrc16[(size_t)d * CAP + r] = (unsigned short)src[e];
                }
            }
        }
        return;
    }
    int id = b - q9 - 1;
    if (id >= 320) {
        int i = (id - 320) * 256 + threadIdx.x;     // float4 index, [0, 1.6M)
        if (i < N_NODES * 32) {
            floatx4 f = ((const floatx4*)x)[i];
            uint2 o;
            o.x = ((unsigned int)f2b(f.y) << 16) | f2b(f.x);
            o.y = ((unsigned int)f2b(f.w) << 16) | f2b(f.z);
            ((uint2*)xb)[i] = o;
        }
        return;
    }
    int t = id * 256 + threadIdx.x;
    const float* W; int NC, l, base;
    if (t < 65536) {
        int mi = t >> 14; l = t & 16383; base = mi << 14; NC = 128;
        W = (mi == 0) ? Ws1 : (mi == 1) ? Wn1 : (mi == 2) ? Ws2 : Wn2;
    } else {
        int u = t - 65536; int mi = u >> 13; l = u & 8191; base = 65536 + (mi << 13); NC = 64;
        W = (mi == 0) ? Ws3 : Wn3;
    }
    int j = l & 7, lane = (l >> 3) & 63, kk = (l >> 9) & 3, c = l >> 11;
    int k = kk * 32 + ((lane >> 4) << 3) + j;
    int n = (c << 4) + (lane & 15);
    wsw[base + l] = f2b(W[k * NC + n]);
}

#define ACC8(q)                                          \
    a[0] += b2f((unsigned short)((q).x & 0xffffu));      \
    a[1] += b2f((unsigned short)((q).x >> 16));          \
    a[2] += b2f((unsigned short)((q).y & 0xffffu));      \
    a[3] += b2f((unsigned short)((q).y >> 16));          \
    a[4] += b2f((unsigned short)((q).z & 0xffffu));      \
    a[5] += b2f((unsigned short)((q).z >> 16));          \
    a[6] += b2f((unsigned short)((q).w & 0xffffu));      \
    a[7] += b2f((unsigned short)((q).w >> 16));

// ---------------- fused layer (1&2): gather means to LDS, then MFMA tile ----------------
// Block owns 64 nodes/rows. Phase 1: wave w gathers nodes w*16+p*4+g (p=0..3) in
// 16-lane groups (lane c = 16B chunk), 8 edges/iter, writes bf16-packed mean to
// LDS (row stride 272 B). Phase 2: wave w computes rows [w*16,w*16+16) x 128;
// A2 frag = LDS chunk kk*4+quad of row m. Gather phase is L3-random-line bound
// (~4 TB/s effective on 64B lines); more per-wave MLP proven flat (r11).
__global__ void layer128_fused(const unsigned short* __restrict__ X,
                               const unsigned short* __restrict__ esrc,
                               const int* __restrict__ cnt,
                               const unsigned short* __restrict__ Wsw1,   // self
                               const unsigned short* __restrict__ Wsw2,   // neigh
                               const float* __restrict__ bias,
                               unsigned short* __restrict__ out, int nrows) {
    __shared__ unsigned short lds[64 * 136];   // 64 rows x 272 B = 17408 B
    int base = blockIdx.x * 64;
    int w = threadIdx.x >> 6;
    int lane = threadIdx.x & 63;
    int g = lane >> 4, c = lane & 15;

    // ---- phase 1: gather ----
    for (int p = 0; p < 4; ++p) {
        int nl = w * 16 + p * 4 + g;
        int node = base + nl;
        if (node < nrows) {
            int nraw = cnt[node];
            int n = min(nraw, CAP);
            const unsigned short* ep = esrc + (size_t)node * CAP;
            float a[8];
#pragma unroll
            for (int i = 0; i < 8; ++i) a[i] = 0.f;
            int j = 0;
            for (; j + 8 <= n; j += 8) {
                int s0 = (int)ep[j],     s1 = (int)ep[j + 1], s2 = (int)ep[j + 2], s3 = (int)ep[j + 3];
                int s4 = (int)ep[j + 4], s5 = (int)ep[j + 5], s6 = (int)ep[j + 6], s7 = (int)ep[j + 7];
                uint4 q0 = *(const uint4*)(X + (size_t)s0 * 128 + c * 8);
                uint4 q1 = *(const uint4*)(X + (size_t)s1 * 128 + c * 8);
                uint4 q2 = *(const uint4*)(X + (size_t)s2 * 128 + c * 8);
                uint4 q3 = *(const uint4*)(X + (size_t)s3 * 128 + c * 8);
                uint4 q4 = *(const uint4*)(X + (size_t)s4 * 128 + c * 8);
                uint4 q5 = *(const uint4*)(X + (size_t)s5 * 128 + c * 8);
                uint4 q6 = *(const uint4*)(X + (size_t)s6 * 128 + c * 8);
                uint4 q7 = *(const uint4*)(X + (size_t)s7 * 128 + c * 8);
                ACC8(q0); ACC8(q1); ACC8(q2); ACC8(q3); ACC8(q4); ACC8(q5); ACC8(q6); ACC8(q7);
            }
            if (j < n) {
                int nm = n - 1;
                int s0 = (int)ep[j],               s1 = (int)ep[min(j + 1, nm)],
                    s2 = (int)ep[min(j + 2, nm)],  s3 = (int)ep[min(j + 3, nm)],
                    s4 = (int)ep[min(j + 4, nm)],  s5 = (int)ep[min(j + 5, nm)],
                    s6 = (int)ep[min(j + 6, nm)],  s7 = (int)ep[min(j + 7, nm)];
                uint4 q0 = *(const uint4*)(X + (size_t)s0 * 128 + c * 8);
                uint4 q1 = *(const uint4*)(X + (size_t)s1 * 128 + c * 8);
                uint4 q2 = *(const uint4*)(X + (size_t)s2 * 128 + c * 8);
                uint4 q3 = *(const uint4*)(X + (size_t)s3 * 128 + c * 8);
                uint4 q4 = *(const uint4*)(X + (size_t)s4 * 128 + c * 8);
                uint4 q5 = *(const uint4*)(X + (size_t)s5 * 128 + c * 8);
                uint4 q6 = *(const uint4*)(X + (size_t)s6 * 128 + c * 8);
                uint4 q7 = *(const uint4*)(X + (size_t)s7 * 128 + c * 8);
                ACC8(q0);
                if (j + 1 < n) { ACC8(q1); }
                if (j + 2 < n) { ACC8(q2); }
                if (j + 3 < n) { ACC8(q3); }
                if (j + 4 < n) { ACC8(q4); }
                if (j + 5 < n) { ACC8(q5); }
                if (j + 6 < n) { ACC8(q6); }
                if (j + 7 < n) { ACC8(q7); }
            }
            float sc = 1.0f / fmaxf((float)nraw, 1.0f);
            uint4 o;
            o.x = ((unsigned int)f2b(a[1] * sc) << 16) | f2b(a[0] * sc);
            o.y = ((unsigned int)f2b(a[3] * sc) << 16) | f2b(a[2] * sc);
            o.z = ((unsigned int)f2b(a[5] * sc) << 16) | f2b(a[4] * sc);
            o.w = ((unsigned int)f2b(a[7] * sc) << 16) | f2b(a[6] * sc);
            *(uint4*)(&lds[nl * 136 + c * 8]) = o;
        }
    }
    __syncthreads();

    // ---- phase 2: gemm ----
    int r0 = base + w * 16;
    if (r0 >= nrows) return;
    int m = lane & 15, quad = lane >> 4;
    int row = r0 + m;

    floatx4 acc[8];
#pragma unroll
    for (int cc = 0; cc < 8; ++cc) acc[cc] = {0.f, 0.f, 0.f, 0.f};

#pragma unroll
    for (int kk = 0; kk < 4; ++kk) {
        short8 a1 = *(const short8*)(X + (size_t)row * 128 + kk * 32 + quad * 8);
        short8 a2 = *(const short8*)(&lds[(w * 16 + m) * 136 + (kk * 4 + quad) * 8]);
#pragma unroll
        for (int cc = 0; cc < 8; ++cc) {
            short8 b1 = *(const short8*)(Wsw1 + (((cc * 4 + kk) * 64 + lane) << 3));
            acc[cc] = __builtin_amdgcn_mfma_f32_16x16x32_bf16(a1, b1, acc[cc], 0, 0, 0);
            short8 b2 = *(const short8*)(Wsw2 + (((cc * 4 + kk) * 64 + lane) << 3));
            acc[cc] = __builtin_amdgcn_mfma_f32_16x16x32_bf16(a2, b2, acc[cc], 0, 0, 0);
        }
    }

#pragma unroll
    for (int r = 0; r < 4; ++r) {
        int orow = r0 + quad * 4 + r;
#pragma unroll
        for (int cc = 0; cc < 8; ++cc) {
            int ocol = cc * 16 + m;
            float v = fmaxf(acc[cc][r] + bias[ocol], 0.f);
            out[(size_t)orow * 128 + ocol] = f2b(v);
        }
    }
}

// ---------------- gather64_final: 8 nodes/wave, 8 edges/iter; out = out_self + mean(t3 rows) ----------------
__global__ void gather64_final(const unsigned short* __restrict__ t3,
                               const unsigned short* __restrict__ esrc,
                               const int* __restrict__ cnt,
                               const float* __restrict__ outself, float* __restrict__ out) {
    int wid = (blockIdx.x * blockDim.x + threadIdx.x) >> 6;
    int lane = threadIdx.x & 63;
    int g = lane >> 3, c = lane & 7;
    int node = wid * 8 + g;
    if (node >= N_NODES) return;
    int nraw = cnt[node];
    int n = min(nraw, CAP);
    const unsigned short* ep = esrc + (size_t)node * CAP;
    float a[8];
#pragma unroll
    for (int i = 0; i < 8; ++i) a[i] = 0.f;
    int j = 0;
    for (; j + 8 <= n; j += 8) {
        int s0 = (int)ep[j],     s1 = (int)ep[j + 1], s2 = (int)ep[j + 2], s3 = (int)ep[j + 3];
        int s4 = (int)ep[j + 4], s5 = (int)ep[j + 5], s6 = (int)ep[j + 6], s7 = (int)ep[j + 7];
        uint4 q0 = *(const uint4*)(t3 + (size_t)s0 * 64 + c * 8);
        uint4 q1 = *(const uint4*)(t3 + (size_t)s1 * 64 + c * 8);
        uint4 q2 = *(const uint4*)(t3 + (size_t)s2 * 64 + c * 8);
        uint4 q3 = *(const uint4*)(t3 + (size_t)s3 * 64 + c * 8);
        uint4 q4 = *(const uint4*)(t3 + (size_t)s4 * 64 + c * 8);
        uint4 q5 = *(const uint4*)(t3 + (size_t)s5 * 64 + c * 8);
        uint4 q6 = *(const uint4*)(t3 + (size_t)s6 * 64 + c * 8);
        uint4 q7 = *(const uint4*)(t3 + (size_t)s7 * 64 + c * 8);
        ACC8(q0); ACC8(q1); ACC8(q2); ACC8(q3); ACC8(q4); ACC8(q5); ACC8(q6); ACC8(q7);
    }
    if (j < n) {
        int nm = n - 1;
        int s0 = (int)ep[j],               s1 = (int)ep[min(j + 1, nm)],
            s2 = (int)ep[min(j + 2, nm)],  s3 = (int)ep[min(j + 3, nm)],
            s4 = (int)ep[min(j + 4, nm)],  s5 = (int)ep[min(j + 5, nm)],
            s6 = (int)ep[min(j + 6, nm)],  s7 = (int)ep[min(j + 7, nm)];
        uint4 q0 = *(const uint4*)(t3 + (size_t)s0 * 64 + c * 8);
        uint4 q1 = *(const uint4*)(t3 + (size_t)s1 * 64 + c * 8);
        uint4 q2 = *(const uint4*)(t3 + (size_t)s2 * 64 + c * 8);
        uint4 q3 = *(const uint4*)(t3 + (size_t)s3 * 64 + c * 8);
        uint4 q4 = *(const uint4*)(t3 + (size_t)s4 * 64 + c * 8);
        uint4 q5 = *(const uint4*)(t3 + (size_t)s5 * 64 + c * 8);
        uint4 q6 = *(const uint4*)(t3 + (size_t)s6 * 64 + c * 8);
        uint4 q7 = *(const uint4*)(t3 + (size_t)s7 * 64 + c * 8);
        ACC8(q0);
        if (j + 1 < n) { ACC8(q1); }
        if (j + 2 < n) { ACC8(q2); }
        if (j + 3 < n) { ACC8(q3); }
        if (j + 4 < n) { ACC8(q4); }
        if (j + 5 < n) { ACC8(q5); }
        if (j + 6 < n) { ACC8(q6); }
        if (j + 7 < n) { ACC8(q7); }
    }
    float sc = 1.0f / fmaxf((float)nraw, 1.0f);
    const float* ip = outself + (size_t)node * 64 + c * 8;
    float* op = out + (size_t)node * 64 + c * 8;
    floatx4 i0 = *(const floatx4*)ip, i1 = *(const floatx4*)(ip + 4);
    floatx4 o0 = {i0.x + a[0] * sc, i0.y + a[1] * sc, i0.z + a[2] * sc, i0.w + a[3] * sc};
    floatx4 o1 = {i1.x + a[4] * sc, i1.y + a[5] * sc, i1.z + a[6] * sc, i1.w + a[7] * sc};
    *(floatx4*)op = o0;
    *(floatx4*)(op + 4) = o1;
}

// ---------------- dual GEMM (layer 3): t3 = h2@Wn3 (bf16), out_self = h2@Ws3 + b3 (fp32) ----------------
__global__ void gemm_dual64(const unsigned short* __restrict__ X,
                            const unsigned short* __restrict__ WswN,
                            const unsigned short* __restrict__ WswS,
                            const float* __restrict__ bias,
                            unsigned short* __restrict__ t3,
                            float* __restrict__ outself, int nrows) {
    int wave = (blockIdx.x * blockDim.x + threadIdx.x) >> 6;
    int r0 = wave * 16;
    if (r0 >= nrows) return;
    int lane = threadIdx.x & 63;
    int m = lane & 15, quad = lane >> 4;
    int row = r0 + m;

    floatx4 accN[4], accS[4];
#pragma unroll
    for (int c = 0; c < 4; ++c) { accN[c] = {0.f, 0.f, 0.f, 0.f}; accS[c] = {0.f, 0.f, 0.f, 0.f}; }

#pragma unroll
    for (int kk = 0; kk < 4; ++kk) {
        short8 a1 = *(const short8*)(X + (size_t)row * 128 + kk * 32 + quad * 8);
#pragma unroll
        for (int c = 0; c < 4; ++c) {
            short8 bn = *(const short8*)(WswN + (((c * 4 + kk) * 64 + lane) << 3));
            accN[c] = __builtin_amdgcn_mfma_f32_16x16x32_bf16(a1, bn, accN[c], 0, 0, 0);
            short8 bs = *(const short8*)(WswS + (((c * 4 + kk) * 64 + lane) << 3));
            accS[c] = __builtin_amdgcn_mfma_f32_16x16x32_bf16(a1, bs, accS[c], 0, 0, 0);
        }
    }

#pragma unroll
    for (int r = 0; r < 4; ++r) {
        int orow = r0 + quad * 4 + r;
#pragma unroll
        for (int c = 0; c < 4; ++c) {
            int ocol = c * 16 + m;
            t3[(size_t)orow * 64 + ocol] = f2b(accN[c][r]);
            outself[(size_t)orow * 64 + ocol] = accS[c][r] + bias[ocol];
        }
    }
}

extern "C" void kernel_launch(void* const* d_in, const int* in_sizes, int n_in,
                              void* d_out, int out_size, void* d_ws, size_t ws_size,
                              hipStream_t stream) {
    const float* x   = (const float*)d_in[0];
    const int* src   = (const int*)d_in[1];
    const int* dst   = (const int*)d_in[2];
    const float* Ws1 = (const float*)d_in[3];
    const float* b1  = (const float*)d_in[4];
    const float* Wn1 = (const float*)d_in[5];
    const float* Ws2 = (const float*)d_in[6];
    const float* b2  = (const float*)d_in[7];
    const float* Wn2 = (const float*)d_in[8];
    const float* Ws3 = (const float*)d_in[9];
    const float* b3  = (const float*)d_in[10];
    const float* Wn3 = (const float*)d_in[11];

    char* ws = (char*)d_ws;
    int* cnt              = (int*)(ws + 0);                   // 200,000 B
    unsigned short* esrc16= (unsigned short*)(ws + 200064);   // 12,800,000 B (50k x CAP x 2B)
    unsigned short* wsw   = (unsigned short*)(ws + 13000064); // 163,840 B
    unsigned short* xb    = (unsigned short*)(ws + 13163904); // 12,800,000 B
    unsigned short* h1    = (unsigned short*)(ws + 25963904); // 12,800,000 B
    float* outself        = (float*)(ws + 38763904);          // 12,800,000 B (50k x 64 f32)
    unsigned short* h2    = xb;    // alias: xb dead after layer-1
    unsigned short* t3    = h1;    // alias: h1 dead after layer-2

    unsigned short* sw_s1 = wsw + 0;
    unsigned short* sw_n1 = wsw + 16384;
    unsigned short* sw_s2 = wsw + 32768;
    unsigned short* sw_n2 = wsw + 49152;
    unsigned short* sw_s3 = wsw + 65536;
    unsigned short* sw_n3 = wsw + 73728;

    const int LAYER_BLOCKS = (N_NODES + 63) / 64;   // 782: 64 nodes/block
    const int GEMM_BLOCKS  = (N_NODES / 16 + 3) / 4;
    const int G64_BLOCKS   = (N_NODES / 8 + 3) / 4;

    hipMemsetAsync(cnt, 0, 200000, stream);
    // grid 7392: edge slots (b%9==0) = 822 >= 782 chunks of 1024 edges; others = 6570
    prep_conv_rs<<<7392, 256, 0, stream>>>(x, xb, Ws1, Wn1, Ws2, Wn2, Ws3, Wn3, wsw,
                                           src, dst, cnt, esrc16);

    // ---- layer 1: h1 = relu(x@Ws1 + b1 + mean_agg(x)@Wn1) ----
    layer128_fused<<<LAYER_BLOCKS, 256, 0, stream>>>(xb, esrc16, cnt, sw_s1, sw_n1, b1, h1, N_NODES);

    // ---- layer 2: h2 = relu(h1@Ws2 + b2 + mean_agg(h1)@Wn2) ----
    layer128_fused<<<LAYER_BLOCKS, 256, 0, stream>>>(h1, esrc16, cnt, sw_s2, sw_n2, b2, h2, N_NODES);

    // ---- layer 3: {t3 = h2@Wn3, out_self = h2@Ws3+b3} ; out = out_self + mean_agg(t3) ----
    gemm_dual64<<<GEMM_BLOCKS, 256, 0, stream>>>(h2, sw_n3, sw_s3, b3, t3, outself, N_NODES);
    gather64_final<<<G64_BLOCKS, 256, 0, stream>>>(t3, esrc16, cnt, outself, (float*)d_out);
}